// Round 13
// baseline (112.484 us; speedup 1.0000x reference)
//
#include <hip/hip_runtime.h>
#include <cmath>

#define BB 4
#define TT 8192
#define DD 1024
#define CL 64                // timesteps per wave-unit (chunk)
#define NCH 128              // chunks per chain (TT/CL)
#define DW 128               // d's per wave (chain width)
#define NDW (DD/DW)          // 8 d-blocks
#define NCHAIN (BB*NDW)      // 32 chains
#define NUNIT (NCHAIN*NCH)   // 4096 wave-units
#define GSZ 16               // chunks per lookback group
#define NGRP (NCH/GSZ)       // 8 groups per chain
#define GRID (NUNIT/4)       // 1024 blocks x 4 waves, all co-resident

typedef float fvec2 __attribute__((ext_vector_type(2)));
typedef unsigned long long u64;

// y[b,t,d] = Re(h[t]),  h[t] = r*h[t-1] + x[t],  r = exp(-|a_d|) * cis(w_d)
//
// Wave-autonomous fused scan. Lessons: the 68us floor = generation lockstep
// (HBM idles during stitch/publish/walk). Here: 4096 independent wave-units,
// all resident at once, ZERO barriers / ZERO LDS. Wave covers 128 d's
// (fvec2/lane = 512B per wave-inst, R1's proven-fast stream shape).
// Two-level lookback (GSZ=16): <=15 within-group preds + <=7 group
// aggregates; group aggs are zero-seeded so they publish after ONE
// parallel within-walk (single latency cascade, not a 128-deep chain).
// Fence-free sc1 protocol (R7): RELAXED agent atomics; per-wave
// s_waitcnt vmcnt(0) orders payload before flag. Rescan re-reads x from
// L3 (proven by R12's FETCH), y leaves via nontemporal stores.

#define CACC(Rr, Ri, mr, mi, Ar, Ai)                                  \
    { float _nr = fmaf(mr, Rr, fmaf(-(mi), Ri, Ar));                  \
      Ri = fmaf(mr, Ri, fmaf(mi, Rr, Ai)); Rr = _nr; }

__global__ __launch_bounds__(256, 4) void fftconv_fused(
    const float* __restrict__ x, const float* __restrict__ decay,
    const float* __restrict__ freq, u64* __restrict__ agg,
    u64* __restrict__ gagg, unsigned* __restrict__ fA,
    unsigned* __restrict__ fG, float* __restrict__ y)
{
    const int tid  = threadIdx.x;
    const int wv   = tid >> 6;
    const int lane = tid & 63;
    const int unit = blockIdx.x*4 + wv;      // deps always at lower unit
    const int c     = unit & (NCH-1);        // chunk (low bits: dispatch order)
    const int chain = unit >> 7;             // NCH=128
    const int dblk  = chain & (NDW-1);
    const int b     = chain >> 3;            // NDW=8
    const int cl    = c & (GSZ-1);           // position in group
    const int g     = c >> 4;                // group index
    const int d0    = dblk*DW + (lane << 1);

    // per-channel constants (2 channels per thread)
    fvec2 dc = *reinterpret_cast<const fvec2*>(decay + d0);
    fvec2 fq = *reinterpret_cast<const fvec2*>(freq + d0);
    float rr[2], ri[2], Mr[2], Mi[2], Pr[2], Pi[2], Qr[2], Qi[2];
#pragma unroll
    for (int ch = 0; ch < 2; ++ch) {
        float a = fabsf(ch ? dc.y : dc.x);
        float w = ch ? fq.y : fq.x;
        float s, co, e;
        e = expf(-a);                sincosf(w, &s, &co);                rr[ch]=e*co; ri[ch]=e*s;  // r
        e = expf(-a*(float)CL);      sincosf(w*(float)CL, &s, &co);      Mr[ch]=e*co; Mi[ch]=e*s;  // M=r^64
        e = expf(-a*(float)(CL*GSZ));sincosf(w*(float)(CL*GSZ), &s, &co);Pr[ch]=e*co; Pi[ch]=e*s;  // P=r^1024
        float tq = (float)(CL*cl);
        e = expf(-a*tq);             sincosf(w*tq, &s, &co);             Qr[ch]=e*co; Qi[ch]=e*s;  // Q=M^cl
    }

    const size_t base = ((size_t)(b*TT + c*CL))*DD + d0;
    const float* xp = x + base;

    // ---- scan from zero (wide 512B/wave-inst reads) ----
    float hr[2] = {0.f,0.f}, hi[2] = {0.f,0.f};
#pragma unroll 8
    for (int t = 0; t < CL; ++t) {
        fvec2 xv = *reinterpret_cast<const fvec2*>(xp + (size_t)t*DD);
#pragma unroll
        for (int ch = 0; ch < 2; ++ch) {
            float xs = ch ? xv.y : xv.x;
            float nr = fmaf(rr[ch], hr[ch], fmaf(-ri[ch], hi[ch], xs));
            hi[ch] = fmaf(rr[ch], hi[ch], ri[ch]*hr[ch]);
            hr[ch] = nr;
        }
    }

    // ---- publish A row (sc1), wave-local drain, flag ----
    u64* arow = agg + ((size_t)chain*NCH + c)*DW + (lane << 1);
#pragma unroll
    for (int ch = 0; ch < 2; ++ch) {
        float2 A = make_float2(hr[ch], hi[ch]);
        u64 raw; __builtin_memcpy(&raw, &A, 8);
        __hip_atomic_store(arow + ch, raw, __ATOMIC_RELAXED, __HIP_MEMORY_SCOPE_AGENT);
    }
    asm volatile("s_waitcnt vmcnt(0)" ::: "memory");
    if (lane == 0)
        __hip_atomic_store(&fA[chain*NCH + c], 1u, __ATOMIC_RELAXED,
                           __HIP_MEMORY_SCOPE_AGENT);

    // ---- poll all needed flags (lane-parallel, wave-autonomous) ----
    {
        const unsigned* wf = nullptr;
        if (lane < cl)                         wf = fA + chain*NCH + (g << 4) + lane;
        else if (lane >= 32 && lane < 32 + g)  wf = fG + chain*NGRP + (lane - 32);
        unsigned done = wf ? 0u : 1u;
        for (;;) {
            if (!done) done = __hip_atomic_load(wf, __ATOMIC_RELAXED,
                                                __HIP_MEMORY_SCOPE_AGENT);
            if (__all(done)) break;
            __builtin_amdgcn_s_sleep(1);
        }
    }
    asm volatile("" ::: "memory");

    // ---- within-group walk: W = sum_{k<cl} M^{cl-1-k} A_k (batched) ----
    float Wr[2] = {0.f,0.f}, Wi[2] = {0.f,0.f};
    const u64* wb = agg + ((size_t)chain*NCH + (g << 4))*DW + (lane << 1);
    {
        u64 qa[8][2];
#pragma unroll
        for (int j = 0; j < 8; ++j)
            if (j < cl) {
                qa[j][0] = __hip_atomic_load(wb + (size_t)j*DW,     __ATOMIC_RELAXED, __HIP_MEMORY_SCOPE_AGENT);
                qa[j][1] = __hip_atomic_load(wb + (size_t)j*DW + 1, __ATOMIC_RELAXED, __HIP_MEMORY_SCOPE_AGENT);
            }
#pragma unroll
        for (int j = 0; j < 8; ++j)
            if (j < cl) {
#pragma unroll
                for (int ch = 0; ch < 2; ++ch) {
                    float2 A; __builtin_memcpy(&A, &qa[j][ch], 8);
                    CACC(Wr[ch], Wi[ch], Mr[ch], Mi[ch], A.x, A.y);
                }
            }
        u64 qb[7][2];
#pragma unroll
        for (int j = 0; j < 7; ++j)
            if (8 + j < cl) {
                qb[j][0] = __hip_atomic_load(wb + (size_t)(8+j)*DW,     __ATOMIC_RELAXED, __HIP_MEMORY_SCOPE_AGENT);
                qb[j][1] = __hip_atomic_load(wb + (size_t)(8+j)*DW + 1, __ATOMIC_RELAXED, __HIP_MEMORY_SCOPE_AGENT);
            }
#pragma unroll
        for (int j = 0; j < 7; ++j)
            if (8 + j < cl) {
#pragma unroll
                for (int ch = 0; ch < 2; ++ch) {
                    float2 A; __builtin_memcpy(&A, &qb[j][ch], 8);
                    CACC(Wr[ch], Wi[ch], Mr[ch], Mi[ch], A.x, A.y);
                }
            }
    }

    // ---- group-aggregate publisher (last chunk of group) ----
    if (cl == GSZ-1) {
        u64* grow = gagg + ((size_t)chain*NGRP + g)*DW + (lane << 1);
#pragma unroll
        for (int ch = 0; ch < 2; ++ch) {
            // GA = M*W + A_own  (inclusive zero-seeded group aggregate)
            float Gr = fmaf(Mr[ch], Wr[ch], fmaf(-Mi[ch], Wi[ch], hr[ch]));
            float Gi = fmaf(Mr[ch], Wi[ch], fmaf( Mi[ch], Wr[ch], hi[ch]));
            float2 G = make_float2(Gr, Gi);
            u64 raw; __builtin_memcpy(&raw, &G, 8);
            __hip_atomic_store(grow + ch, raw, __ATOMIC_RELAXED, __HIP_MEMORY_SCOPE_AGENT);
        }
        asm volatile("s_waitcnt vmcnt(0)" ::: "memory");
        if (lane == 0)
            __hip_atomic_store(&fG[chain*NGRP + g], 1u, __ATOMIC_RELAXED,
                               __HIP_MEMORY_SCOPE_AGENT);
    }

    // ---- group walk: S = sum_{g'<g} P^{g-1-g'} GA_{g'} (batched) ----
    float Sr[2] = {0.f,0.f}, Si[2] = {0.f,0.f};
    const u64* gb = gagg + ((size_t)chain*NGRP)*DW + (lane << 1);
    {
        u64 qg[NGRP-1][2];
#pragma unroll
        for (int j = 0; j < NGRP-1; ++j)
            if (j < g) {
                qg[j][0] = __hip_atomic_load(gb + (size_t)j*DW,     __ATOMIC_RELAXED, __HIP_MEMORY_SCOPE_AGENT);
                qg[j][1] = __hip_atomic_load(gb + (size_t)j*DW + 1, __ATOMIC_RELAXED, __HIP_MEMORY_SCOPE_AGENT);
            }
#pragma unroll
        for (int j = 0; j < NGRP-1; ++j)
            if (j < g) {
#pragma unroll
                for (int ch = 0; ch < 2; ++ch) {
                    float2 A; __builtin_memcpy(&A, &qg[j][ch], 8);
                    CACC(Sr[ch], Si[ch], Pr[ch], Pi[ch], A.x, A.y);
                }
            }
    }

    // ---- seed E = Q*S + W; rescan x (L3-hot) and write y ----
    const float* xp2 = x + base;
    asm volatile("" : "+v"(xp2));            // opaque: forbid cross-pass reg reuse
    float* yp = y + base;
#pragma unroll
    for (int ch = 0; ch < 2; ++ch) {
        hr[ch] = fmaf(Qr[ch], Sr[ch], fmaf(-Qi[ch], Si[ch], Wr[ch]));
        hi[ch] = fmaf(Qr[ch], Si[ch], fmaf( Qi[ch], Sr[ch], Wi[ch]));
    }
#pragma unroll 8
    for (int t = 0; t < CL; ++t) {
        fvec2 xv = *reinterpret_cast<const fvec2*>(xp2 + (size_t)t*DD);
        fvec2 yv;
#pragma unroll
        for (int ch = 0; ch < 2; ++ch) {
            float xs = ch ? xv.y : xv.x;
            float nr = fmaf(rr[ch], hr[ch], fmaf(-ri[ch], hi[ch], xs));
            hi[ch] = fmaf(rr[ch], hi[ch], ri[ch]*hr[ch]);
            hr[ch] = nr;
            if (ch) yv.y = nr; else yv.x = nr;
        }
        __builtin_nontemporal_store(yv, reinterpret_cast<fvec2*>(yp + (size_t)t*DD));
    }
}

extern "C" void kernel_launch(void* const* d_in, const int* in_sizes, int n_in,
                              void* d_out, int out_size, void* d_ws, size_t ws_size,
                              hipStream_t stream) {
    const float* x     = (const float*)d_in[0];
    const float* decay = (const float*)d_in[1];
    const float* freq  = (const float*)d_in[2];
    float*       y     = (float*)d_out;

    u64*      agg  = (u64*)d_ws;                               // 32*128*128*8 = 4 MB
    u64*      gagg = agg  + (size_t)NCHAIN*NCH*DW;             // 32*8*128*8 = 256 KB
    unsigned* fA   = (unsigned*)(gagg + (size_t)NCHAIN*NGRP*DW);
    unsigned* fG   = fA + NCHAIN*NCH;                          // 4096 + 256 u32

    // zero both flag arrays (contiguous) each launch; kernel-boundary
    // release makes the zeros visible to the kernel's sc1 reads.
    (void)hipMemsetAsync(fA, 0, (NCHAIN*NCH + NCHAIN*NGRP)*sizeof(unsigned), stream);
    fftconv_fused<<<GRID, 256, 0, stream>>>(x, decay, freq, agg, gagg, fA, fG, y);
}

// Round 15
// 67.153 us; speedup vs baseline: 1.6750x; 1.6750x over previous
//
#include <hip/hip_runtime.h>
#include <cmath>

#define BB 4
#define TT 8192
#define DD 1024
#define CL 256               // timesteps per chunk (= per block)
#define DBLK 32              // d's per block
#define NCH (TT/CL)          // 32 chunks per chain
#define NDB (DD/DBLK)        // 32 d-blocks
#define NCHAIN (BB*NDB)      // 128 chains
#define NBLK (NCHAIN*NCH)    // 4096 blocks
#define NPART 8              // t-parts (32 lanes each)
#define PLEN (CL/NPART)      // 32 steps per part

typedef float fvec4 __attribute__((ext_vector_type(4)));
typedef unsigned long long u64;

// y[b,t,d] = Re(h[t]),  h[t] = r*h[t-1] + x[t],  r = exp(-|a_d|) * cis(w_d)
//
// R13 theory: plain (relaxed-agent) poll loads cache the stale pre-publish
// flag in the XCD L2 and spin on it until eviction -> the ~68us floor.
// R14 lesson (rule #18): a STANDALONE inline-asm s_waitcnt does NOT stop
// hipcc from hoisting register-only consumers above it -> garbage reads.
// Fix here: (a) flag loads fuse the waitcnt INTO the load asm;
//           (b) batched agg loads are pinned by a "+v" waitcnt asm that
//               consumers data-depend on, + sched_barrier(0).
// All sync ops use sc0 sc1 (L2-bypassing, L3-coherent). Structure = R9.

__device__ __forceinline__ void st_sys_u32(unsigned* p, unsigned v) {
    asm volatile("global_store_dword %0, %1, off sc0 sc1"
                 :: "v"(p), "v"(v) : "memory");
}
__device__ __forceinline__ unsigned ld_flag_wait(const unsigned* p) {
    unsigned v;
    asm volatile("global_load_dword %0, %1, off sc0 sc1\n\t"
                 "s_waitcnt vmcnt(0)"
                 : "=&v"(v) : "v"(p) : "memory");
    return v;                               // valid: wait fused in-asm
}
__device__ __forceinline__ void st_sys_u64(u64* p, u64 v) {
    asm volatile("global_store_dwordx2 %0, %1, off sc0 sc1"
                 :: "v"(p), "v"(v) : "memory");
}
__device__ __forceinline__ u64 ld_agg(const u64* p) {     // async: pin before use!
    u64 v;
    asm volatile("global_load_dwordx2 %0, %1, off sc0 sc1"
                 : "=&v"(v) : "v"(p) : "memory");
    return v;
}
__device__ __forceinline__ u64 ld_agg_wait(const u64* p) {
    u64 v;
    asm volatile("global_load_dwordx2 %0, %1, off sc0 sc1\n\t"
                 "s_waitcnt vmcnt(0)"
                 : "=&v"(v) : "v"(p) : "memory");
    return v;
}

__global__ __launch_bounds__(256, 4) void fftconv_fused(
    const float* __restrict__ x, const float* __restrict__ decay,
    const float* __restrict__ freq, u64* __restrict__ agg,
    unsigned* __restrict__ flags, float* __restrict__ y)
{
    __shared__ float tile[CL*DBLK];        // 32 KB
    __shared__ float2 Ssub[NPART][DBLK];   // 2 KB
    __shared__ float2 eoff[NPART][DBLK];   // 2 KB
    __shared__ float2 Ebc[DBLK];           // 256 B

    const int tid  = threadIdx.x;
    const int l32  = tid & 31;             // d-lane
    const int part = tid >> 5;             // 0..7 (t-part)
    const int bid  = blockIdx.x;
    const int c     = bid & (NCH-1);       // chunk index (low bits: dispatch order!)
    const int chain = bid >> 5;            // NCH=32
    const int dblk  = chain & (NDB-1);
    const int b     = chain >> 5;          // NDB=32

    const int d = dblk*DBLK + l32;
    const size_t xoff = ((size_t)(b*TT + c*CL))*DD + (size_t)dblk*DBLK;

    // per-d constants
    const float a = fabsf(decay[d]);
    const float w = freq[d];
    float s_, c_;
    float e = expf(-a); sincosf(w, &s_, &c_);
    const float rr = e*c_, ri = e*s_;                     // r
    e = expf(-a*(float)PLEN); sincosf(w*(float)PLEN, &s_, &c_);
    const float Msr = e*c_, Msi = e*s_;                   // r^PLEN
    e = expf(-a*(float)CL); sincosf(w*(float)CL, &s_, &c_);
    const float Mr = e*c_, Mi = e*s_;                     // r^CL
    e = expf(-a*(float)(PLEN*part)); sincosf(w*(float)(PLEN*part), &s_, &c_);
    const float Mpr = e*c_, Mpi = e*s_;                   // r^(PLEN*part)

    // ---- stage x tile into LDS (fvec4, coalesced) ----
    {
        const float* xb = x + xoff;
#pragma unroll
        for (int k = 0; k < 8; ++k) {
            int t  = k*32 + (tid >> 3);
            int dq = (tid & 7) << 2;
            fvec4 v = *reinterpret_cast<const fvec4*>(xb + (size_t)t*DD + dq);
            *reinterpret_cast<fvec4*>(&tile[t*DBLK + dq]) = v;
        }
    }
    __syncthreads();

    // ---- local scan from zero; real-part history in registers ----
    float hRr[PLEN];
    {
        float hr = 0.f, hi = 0.f;
        const int rowbase = part*PLEN;
#pragma unroll
        for (int t = 0; t < PLEN; ++t) {
            float xv = tile[(rowbase + t)*DBLK + l32];
            float nr = fmaf(rr, hr, fmaf(-ri, hi, xv));
            hi = fmaf(rr, hi, ri*hr);
            hr = nr;
            hRr[t] = hr;
        }
        Ssub[part][l32] = make_float2(hr, hi);
    }
    __syncthreads();

    // ---- tid<32: stitch, publish (sc1), poll (sc1), walk (sc1) ----
    if (tid < 32) {
        float Lr = 0.f, Li = 0.f;
#pragma unroll
        for (int p = 0; p < NPART; ++p) {
            eoff[p][l32] = make_float2(Lr, Li);
            float2 Sp = Ssub[p][l32];
            float nr = fmaf(Msr, Lr, fmaf(-Msi, Li, Sp.x));
            Li = fmaf(Msr, Li, fmaf(Msi, Lr, Sp.y));
            Lr = nr;
        }
        // chunk aggregate A (state after CL steps from zero)
        {
            float2 Av = make_float2(Lr, Li);
            u64 raw; __builtin_memcpy(&raw, &Av, 8);
            st_sys_u64(&agg[(size_t)bid*DBLK + l32], raw);
        }
        asm volatile("s_waitcnt vmcnt(0)" ::: "memory");  // stores only: safe
        if (l32 == 0)
            st_sys_u32(&flags[bid], 1u);

        const int cbase = chain*NCH;       // == bid - c

        // lane-parallel poll: lane j re-reads flag j from L3 each iter
        // (waitcnt fused inside the load asm -> value valid).
        if (l32 < c) {
            while (ld_flag_wait(&flags[cbase + l32]) == 0u)
                __builtin_amdgcn_s_sleep(2);
        }

        float Er = 0.f, Ei = 0.f;
        int j = 0;
        while (j + 8 <= c) {               // batches of 8: overlap L3 latency
            u64 q[8];
#pragma unroll
            for (int t = 0; t < 8; ++t)
                q[t] = ld_agg(&agg[(size_t)(cbase + j + t)*DBLK + l32]);
            // pin: consumers must use post-wait values (rule #18 fix)
            asm volatile("s_waitcnt vmcnt(0)"
                         : "+v"(q[0]), "+v"(q[1]), "+v"(q[2]), "+v"(q[3]),
                           "+v"(q[4]), "+v"(q[5]), "+v"(q[6]), "+v"(q[7])
                         :: "memory");
            __builtin_amdgcn_sched_barrier(0);
#pragma unroll
            for (int t = 0; t < 8; ++t) {
                float2 A; __builtin_memcpy(&A, &q[t], 8);
                float nr = fmaf(Mr, Er, fmaf(-Mi, Ei, A.x));
                Ei = fmaf(Mr, Ei, fmaf(Mi, Er, A.y));
                Er = nr;
            }
            j += 8;
        }
        for (; j < c; ++j) {
            u64 raw2 = ld_agg_wait(&agg[(size_t)(cbase + j)*DBLK + l32]);
            float2 A; __builtin_memcpy(&A, &raw2, 8);
            float nr = fmaf(Mr, Er, fmaf(-Mi, Ei, A.x));
            Ei = fmaf(Mr, Ei, fmaf(Mi, Er, A.y));
            Er = nr;
        }
        Ebc[l32] = make_float2(Er, Ei);
    }
    __syncthreads();

    // ---- finish: S = eoff[part] + r^(PLEN*part)*E; y[t] = hRr[t] + Re(r^(t+1) S) ----
    {
        float2 Ev = Ebc[l32];
        float2 ev = eoff[part][l32];
        float Sr = ev.x + (Mpr*Ev.x - Mpi*Ev.y);
        float Si = ev.y + (Mpr*Ev.y + Mpi*Ev.x);
        float wr = rr*Sr - ri*Si;          // w = r * S
        float wi = rr*Si + ri*Sr;
        float* yp = y + xoff + (size_t)(part*PLEN)*DD + l32;
#pragma unroll
        for (int t = 0; t < PLEN; ++t) {
            __builtin_nontemporal_store(hRr[t] + wr, yp);
            yp += DD;
            float nwr = rr*wr - ri*wi;     // w *= r
            wi = rr*wi + ri*wr;
            wr = nwr;
        }
    }
}

extern "C" void kernel_launch(void* const* d_in, const int* in_sizes, int n_in,
                              void* d_out, int out_size, void* d_ws, size_t ws_size,
                              hipStream_t stream) {
    const float* x     = (const float*)d_in[0];
    const float* decay = (const float*)d_in[1];
    const float* freq  = (const float*)d_in[2];
    float*       y     = (float*)d_out;

    u64*      agg   = (u64*)d_ws;                             // 4096*32*8 = 1 MB
    unsigned* flags = (unsigned*)((char*)d_ws + (size_t)NBLK*DBLK*sizeof(u64));

    // zero the lookback flags each launch (capture-legal async memset);
    // dispatch-boundary writeback makes the zeros L3-visible to sc1 reads.
    (void)hipMemsetAsync(flags, 0, NBLK*sizeof(unsigned), stream);
    fftconv_fused<<<NBLK, 256, 0, stream>>>(x, decay, freq, agg, flags, y);
}

// Round 16
// 50.708 us; speedup vs baseline: 2.2182x; 1.3243x over previous
//
#include <hip/hip_runtime.h>
#include <cmath>

#define BB 4
#define TT 8192
#define DD 1024
#define DBLK 16              // d's per block (chain width)
#define NDB (DD/DBLK)        // 64 d-blocks
#define NCHAIN (BB*NDB)      // 256 chains == 256 blocks == 1 per CU
#define CL 1024              // timesteps per chunk
#define NITER (TT/CL)        // 8 chunks, carry in registers
#define NTHR 512             // 8 waves
#define NPART (NTHR/DBLK)    // 32 t-parts
#define PLEN (CL/NPART)      // 32 steps per part

// y[b,t,d] = Re(h[t]),  h[t] = r*h[t-1] + x[t],  r = exp(-|a_d|) * cis(w_d)
//
// PERSISTENT-CHAIN version. R1..R15 post-mortem: every lookback variant
// (any sync flavor, any topology) lands 67-73us because co-resident blocks
// run stage/scan/sync/finish in lockstep -> HBM alternates read-burst /
// idle / write-burst. Here each block owns a full chain and carries state
// across 8 chunk-iterations IN REGISTERS: no flags, no lookback, no global
// sync, no per-launch memset. Double-buffered LDS tile + global_load_lds
// prefetch 1 chunk ahead; raw s_barrier + counted s_waitcnt vmcnt(32)
// (NOT __syncthreads, which drains vmcnt(0) and serializes the pipeline):
// the 8 stage loads (older) complete while 32 y-stores (newer) fly ->
// HBM sees continuous mixed reads+writes.
// DBLK=16 -> 64B granules; XCD-pairing swizzle puts sibling d-blocks on
// the same XCD so their 64B halves merge into full 128B lines in that
// XCD's L2 (plain stores, not nontemporal, for the same reason).

__global__ __launch_bounds__(NTHR, 2) void fftconv_persist(
    const float* __restrict__ x, const float* __restrict__ decay,
    const float* __restrict__ freq, float* __restrict__ y)
{
    __shared__ float  tile[2][CL*DBLK];    // 128 KB (double buffer)
    __shared__ float2 Ssub[NPART][DBLK];   // 4 KB  per-part sub-aggregates
    __shared__ float2 eoff[NPART][DBLK];   // 4 KB  exclusive in-chunk offsets
    __shared__ float2 HB[DBLK];            // 128 B carry broadcast

    const int tid  = threadIdx.x;
    const int l16  = tid & 15;             // d-lane
    const int part = tid >> 4;             // 0..31 (t-part)
    const int wv   = tid >> 6;             // wave 0..7
    const int wl   = tid & 63;             // lane in wave
    const int bid  = blockIdx.x;
    // XCD-pairing swizzle: sibling chains (2j,2j+1) land on the same XCD
    // (bid%8 ~ XCD); 32 consecutive chains share an XCD.
    const int chain = (bid & 7)*32 + (bid >> 3);
    const int dblk  = chain & (NDB-1);
    const int b     = chain >> 6;          // NDB=64
    const int d     = dblk*DBLK + l16;

    // per-d constants (computed ONCE per block, reused for 8 chunks)
    const float a = fabsf(decay[d]);
    const float w = freq[d];
    float s_, c_, e;
    e = expf(-a);                    sincosf(w, &s_, &c_);
    const float rr = e*c_, ri = e*s_;                         // r
    e = expf(-a*(float)PLEN);        sincosf(w*(float)PLEN, &s_, &c_);
    const float Msr = e*c_, Msi = e*s_;                       // r^32  (part step)
    e = expf(-a*(float)CL);          sincosf(w*(float)CL, &s_, &c_);
    const float Mcr = e*c_, Mci = e*s_;                       // r^1024 (chunk step)
    e = expf(-a*(float)(PLEN*part)); sincosf(w*(float)(PLEN*part), &s_, &c_);
    const float Mpr = e*c_, Mpi = e*s_;                       // r^(32*part)

    const float* xch = x + (size_t)b*TT*DD + dblk*DBLK;
    float*       ych = y + (size_t)b*TT*DD + dblk*DBLK;

    // stage chunk k into tile[buf]: 8 global_load_lds x 16B per wave.
    // LDS dest is wave-uniform base + lane*16 (HW rule) == rows r0..r0+15
    // of the [1024][16] tile; per-lane global src matches that layout.
    auto stage = [&](int k, int buf) {
        const float* xc = xch + (size_t)(k*CL)*DD;
        const int rofs = wl >> 2;
        const int gofs = (wl & 3) << 2;
#pragma unroll
        for (int i = 0; i < 8; ++i) {
            const int r0 = (wv*8 + i)*16;
            __builtin_amdgcn_global_load_lds(
                (const __attribute__((address_space(1))) void*)
                    (xc + (size_t)(r0 + rofs)*DD + gofs),
                (__attribute__((address_space(3))) void*)&tile[buf][r0*DBLK],
                16, 0, 0);
        }
    };

    float Hr = 0.f, Hi = 0.f;              // chain carry (lives in tid<16)

    stage(0, 0);                           // prologue
    asm volatile("s_waitcnt vmcnt(0)" ::: "memory");
    __builtin_amdgcn_s_barrier();
    __builtin_amdgcn_sched_barrier(0);

    for (int k = 0; k < NITER; ++k) {
        const int cur = k & 1;

        // ---- scan from zero; real-part history in registers ----
        float hRr[PLEN];
        {
            float hr = 0.f, hi = 0.f;
            const int rowbase = part*PLEN;
#pragma unroll
            for (int t = 0; t < PLEN; ++t) {
                float xv = tile[cur][(rowbase + t)*DBLK + l16];
                float nr = fmaf(rr, hr, fmaf(-ri, hi, xv));
                hi = fmaf(rr, hi, ri*hr);
                hr = nr;
                hRr[t] = hr;
            }
            Ssub[part][l16] = make_float2(hr, hi);
        }
        asm volatile("s_waitcnt lgkmcnt(0)" ::: "memory");
        __builtin_amdgcn_s_barrier();                    // B2: Ssub visible
        __builtin_amdgcn_sched_barrier(0);

        // ---- prefetch next chunk (reads fly under stitch+finish) ----
        if (k + 1 < NITER) stage(k + 1, cur ^ 1);

        // ---- stitch (16 lanes): exclusive offsets + carry update ----
        if (tid < DBLK) {
            float Lr = 0.f, Li = 0.f;
#pragma unroll
            for (int p = 0; p < NPART; ++p) {
                eoff[p][l16] = make_float2(Lr, Li);
                float2 Sp = Ssub[p][l16];
                float nr = fmaf(Msr, Lr, fmaf(-Msi, Li, Sp.x));
                Li = fmaf(Msr, Li, fmaf(Msi, Lr, Sp.y));
                Lr = nr;
            }
            HB[l16] = make_float2(Hr, Hi);  // carry INTO this chunk
            // H = A + Mc*H  (A = Lr,Li = zero-seeded chunk aggregate)
            float nHr = fmaf(Mcr, Hr, fmaf(-Mci, Hi, Lr));
            Hi = fmaf(Mcr, Hi, fmaf(Mci, Hr, Li));
            Hr = nHr;
        }
        asm volatile("s_waitcnt lgkmcnt(0)" ::: "memory");
        __builtin_amdgcn_s_barrier();                    // B3: eoff/HB visible
        __builtin_amdgcn_sched_barrier(0);

        // ---- finish: S = eoff + r^(32*part)*H_in; y[t] = hRr[t] + Re(r^(t+1) S) ----
        {
            float2 Hp = HB[l16];
            float2 eo = eoff[part][l16];
            float Sr = eo.x + (Mpr*Hp.x - Mpi*Hp.y);
            float Si = eo.y + (Mpr*Hp.y + Mpi*Hp.x);
            float wr = rr*Sr - ri*Si;      // w = r * S
            float wi = rr*Si + ri*Sr;
            float* yp = ych + (size_t)(k*CL + part*PLEN)*DD + l16;
#pragma unroll
            for (int t = 0; t < PLEN; ++t) {
                yp[(size_t)t*DD] = hRr[t] + wr;   // plain store: L2 line-merge
                float nwr = rr*wr - ri*wi;        // w *= r
                wi = rr*wi + ri*wr;
                wr = nwr;
            }
        }

        // ---- counted wait: stage(k+1) [8 oldest] done; 32 y-stores fly ----
        if (k + 1 < NITER) {
            asm volatile("s_waitcnt vmcnt(32)" ::: "memory");
            __builtin_amdgcn_s_barrier();                // B1: tile[nxt] ready
            __builtin_amdgcn_sched_barrier(0);
        }
    }
}

extern "C" void kernel_launch(void* const* d_in, const int* in_sizes, int n_in,
                              void* d_out, int out_size, void* d_ws, size_t ws_size,
                              hipStream_t stream) {
    const float* x     = (const float*)d_in[0];
    const float* decay = (const float*)d_in[1];
    const float* freq  = (const float*)d_in[2];
    float*       y     = (float*)d_out;

    // single dispatch; no workspace, no flags, no memset
    fftconv_persist<<<NCHAIN, NTHR, 0, stream>>>(x, decay, freq, y);
}